// Round 2
// baseline (871.699 us; speedup 1.0000x reference)
//
#include <hip/hip_runtime.h>

typedef unsigned int u32;
typedef unsigned short u16;
typedef __attribute__((ext_vector_type(8))) __bf16 bf16x8;
typedef __attribute__((ext_vector_type(4))) float f32x4;

#define NB 16384
#define NM 4096
#define ND 512
#define NOUT 128

// ---------- helpers ----------
__device__ __forceinline__ u16 f2bf(float f) {
  u32 u = __float_as_uint(f);
  u += 0x7FFFu + ((u >> 16) & 1u);   // RNE
  return (u16)(u >> 16);
}

__device__ __forceinline__ void stage16(const u16* g, u16* l) {
  __builtin_amdgcn_global_load_lds((__attribute__((address_space(1))) void*)g,
                                   (__attribute__((address_space(3))) void*)l,
                                   16, 0, 0);
}

__device__ __forceinline__ uint4 pack8(float4 v0, float4 v1) {
  uint4 pk;
  pk.x = (u32)f2bf(v0.x) | ((u32)f2bf(v0.y) << 16);
  pk.y = (u32)f2bf(v0.z) | ((u32)f2bf(v0.w) << 16);
  pk.z = (u32)f2bf(v1.x) | ((u32)f2bf(v1.y) << 16);
  pk.w = (u32)f2bf(v1.z) | ((u32)f2bf(v1.w) << 16);
  return pk;
}

// ---------- prep_x: coalesced read -> LDS transpose -> coalesced write ----------
// 256 blocks x 64 rows. x_ws layout [rbig(128)][kg(64)][row(128)][8]
__global__ __launch_bounds__(256) void prep_x(const float* __restrict__ x,
                                              u16* __restrict__ x_ws,
                                              float* __restrict__ x2) {
  __shared__ uint4 t[64 * 64];   // 64 KB, XOR-swizzled: t[kg*64 + ((row+kg)&63)]
  const int tid = threadIdx.x, blk = blockIdx.x;
  const int lane = tid & 63, w = tid >> 6;
  const int rbig = blk >> 1, sub = blk & 1;

  #pragma unroll 4
  for (int p = 0; p < 16; ++p) {
    const int rl = p * 4 + w;                       // local row 0..63
    const float* src = x + (size_t)(blk * 64 + rl) * ND + lane * 8;
    float4 v0 = *(const float4*)src;
    float4 v1 = *(const float4*)(src + 4);
    float ss = v0.x*v0.x + v0.y*v0.y + v0.z*v0.z + v0.w*v0.w
             + v1.x*v1.x + v1.y*v1.y + v1.z*v1.z + v1.w*v1.w;
    #pragma unroll
    for (int off = 32; off > 0; off >>= 1) ss += __shfl_down(ss, off);
    if (lane == 0) x2[blk * 64 + rl] = ss;
    t[lane * 64 + ((rl + lane) & 63)] = pack8(v0, v1);   // kg = lane
  }
  __syncthreads();
  #pragma unroll 4
  for (int it = 0; it < 16; ++it) {
    const int kg = it * 4 + w;
    uint4 pk = t[kg * 64 + ((lane + kg) & 63)];          // row = lane
    *(uint4*)&x_ws[(((size_t)(rbig * 64 + kg)) * 128 + sub * 64 + lane) * 8] = pk;
  }
}

// ---------- prep_s: same structure, 64 blocks. s_ws [mb(32)][kg(64)][m(128)][8] ----------
__global__ __launch_bounds__(256) void prep_s(const float* __restrict__ s,
                                              u16* __restrict__ s_ws,
                                              float* __restrict__ s2) {
  __shared__ uint4 t[64 * 64];
  const int tid = threadIdx.x, blk = blockIdx.x;
  const int lane = tid & 63, w = tid >> 6;
  const int mb = blk >> 1, sub = blk & 1;

  #pragma unroll 4
  for (int p = 0; p < 16; ++p) {
    const int rl = p * 4 + w;
    const float* src = s + (size_t)(blk * 64 + rl) * ND + lane * 8;
    float4 v0 = *(const float4*)src;
    float4 v1 = *(const float4*)(src + 4);
    float ss = v0.x*v0.x + v0.y*v0.y + v0.z*v0.z + v0.w*v0.w
             + v1.x*v1.x + v1.y*v1.y + v1.z*v1.z + v1.w*v1.w;
    #pragma unroll
    for (int off = 32; off > 0; off >>= 1) ss += __shfl_down(ss, off);
    if (lane == 0) s2[blk * 64 + rl] = ss;
    t[lane * 64 + ((rl + lane) & 63)] = pack8(v0, v1);
  }
  __syncthreads();
  #pragma unroll 4
  for (int it = 0; it < 16; ++it) {
    const int kg = it * 4 + w;
    uint4 pk = t[kg * 64 + ((lane + kg) & 63)];
    *(uint4*)&s_ws[(((size_t)(mb * 64 + kg)) * 128 + sub * 64 + lane) * 8] = pk;
  }
}

// ---------- prep_hw: 32 blocks, m-chunk of 128. hw_ws [slab=(mb*16+kg)][o(128)][8] ----------
__global__ __launch_bounds__(256) void prep_hw(const float* __restrict__ hw,
                                               u16* __restrict__ hw_ws) {
  __shared__ uint4 t[128 * 16];   // 32 KB, swizzled t[o*16 + ((kg+o)&15)]
  const int tid = threadIdx.x, blk = blockIdx.x;
  #pragma unroll
  for (int p = 0; p < 8; ++p) {
    const int o = p * 16 + (tid >> 4);
    const int kg = tid & 15;
    const float* src = hw + (size_t)o * NM + blk * 128 + kg * 8;
    float4 v0 = *(const float4*)src;
    float4 v1 = *(const float4*)(src + 4);
    t[o * 16 + ((kg + o) & 15)] = pack8(v0, v1);
  }
  __syncthreads();
  #pragma unroll
  for (int it = 0; it < 8; ++it) {
    const int kg = it * 2 + (tid >> 7);
    const int o = tid & 127;
    uint4 pk = t[o * 16 + ((kg + o) & 15)];
    *(uint4*)&hw_ws[(((size_t)(blk * 16 + kg)) * 128 + o) * 8] = pk;
  }
}

// ---------- main fused kernel ----------
// grid 1024: rb = bid>>3 (128 row-blocks of 128 rows), half = bid&7 (M split 8x, 4 mtiles each)
// block 256 = 4 waves; wave tile 64x64 (4x4 16x16x32 mfma frags)
// LDS 32 KB: Xbuf[2] (8 KB ea) + Sbuf[2] (8 KB ea); Ks (16 KB) aliases buf1 (dead at epilogue;
// in-flight staging at mt boundaries always targets buf0).
__global__ __launch_bounds__(256, 4)
void rbf_fused(const u16* __restrict__ x_ws, const u16* __restrict__ s_ws,
               const u16* __restrict__ hw_ws, const float* __restrict__ x2,
               const float* __restrict__ s2, const float* __restrict__ gamma_p,
               const float* __restrict__ head_b, const float* __restrict__ scale_p,
               const float* __restrict__ shift_p, float* __restrict__ out)
{
  __shared__ __align__(16) u16 smem[16384];   // 32 KB
  // X buf b: b*4096 ; S buf b: 8192 + b*4096  (u16 units; kg stride 1024 = 128 rows * 8)

  const int tid  = threadIdx.x;
  const int w    = tid >> 6;
  const int lane = tid & 63;
  const int quad = lane >> 4;
  const int l16  = lane & 15;
  const int wr   = w & 1;
  const int wc   = w >> 1;
  const int rb   = blockIdx.x >> 3;
  const int half = blockIdx.x & 7;
  const int b0   = rb * 128;

  const float gamma  = gamma_p[0];
  const float vscale = scale_p[0];
  const float vshift = shift_p[0];

  float x2v[4][4];
  #pragma unroll
  for (int r = 0; r < 4; ++r)
    #pragma unroll
    for (int i = 0; i < 4; ++i)
      x2v[r][i] = x2[b0 + wr * 64 + r * 16 + quad * 4 + i];

  const f32x4 zf = {0.f, 0.f, 0.f, 0.f};
  f32x4 acc_xs[4][4];
  f32x4 acc_out[4][4];
  #pragma unroll
  for (int r = 0; r < 4; ++r)
    #pragma unroll
    for (int c = 0; c < 4; ++c) { acc_xs[r][c] = zf; acc_out[r][c] = zf; }

  // Ks region: kg<4 lives in Xbuf[1], kg>=4 in Sbuf[1] (each kg = 1024 u16)
  auto ks_base = [&](int kg) { return (kg < 4) ? (4096 + kg * 1024) : (12288 + (kg - 4) * 1024); };

  auto stage_chunk = [&](int g) {
    const int kc  = g & 15;
    const int mt  = g >> 4;
    const int buf = g & 1;
    const int mtg = half * 4 + mt;
    #pragma unroll
    for (int t = 0; t < 4; ++t) {
      const int i = (t << 2) | w;       // wave-uniform slab id 0..15
      if (i < 8) {
        const int kgl = i >> 1, sub = i & 1;
        const int kgg = kc * 4 + kgl;
        const u16* src = x_ws + (((size_t)(rb * 64 + kgg)) * 128 + sub * 64 + lane) * 8;
        stage16(src, &smem[buf * 4096 + (kgl * 128 + sub * 64 + lane) * 8]);
      } else {
        const int j = i - 8;
        const int kgl = j >> 1, sub = j & 1;
        const int kgg = kc * 4 + kgl;
        const u16* src = s_ws + (((size_t)(mtg * 64 + kgg)) * 128 + sub * 64 + lane) * 8;
        stage16(src, &smem[8192 + buf * 4096 + (kgl * 128 + sub * 64 + lane) * 8]);
      }
    }
  };

  auto compute_chunk = [&](int buf) {
    bf16x8 av[4], bv[4];
    #pragma unroll
    for (int r = 0; r < 4; ++r)
      av[r] = *(const bf16x8*)&smem[buf * 4096 + (quad * 128 + wr * 64 + r * 16 + l16) * 8];
    #pragma unroll
    for (int c = 0; c < 4; ++c)
      bv[c] = *(const bf16x8*)&smem[8192 + buf * 4096 + (quad * 128 + wc * 64 + c * 16 + l16) * 8];
    #pragma unroll
    for (int r = 0; r < 4; ++r)
      #pragma unroll
      for (int c = 0; c < 4; ++c)
        acc_xs[r][c] = __builtin_amdgcn_mfma_f32_16x16x32_bf16(av[r], bv[c], acc_xs[r][c], 0, 0, 0);
  };

  stage_chunk(0);
  __syncthreads();

  #pragma unroll 1
  for (int mt = 0; mt < 4; ++mt) {
    const int mtg = half * 4 + mt;
    #pragma unroll 2
    for (int kc = 0; kc < 16; ++kc) {
      const int g = (mt << 4) | kc;
      if (g + 1 < 64) stage_chunk(g + 1);
      compute_chunk(g & 1);
      __syncthreads();
    }

    float s2v[4];
    #pragma unroll
    for (int c = 0; c < 4; ++c)
      s2v[c] = s2[mtg * 128 + wc * 64 + c * 16 + l16];

    // two passes: p-th 64 k-columns of this mtile
    #pragma unroll 1
    for (int p = 0; p < 2; ++p) {
      if (wc == p) {
        // epilogue: this wave's acc_xs covers exactly cols p*64..p*64+63
        #pragma unroll
        for (int r = 0; r < 4; ++r)
          #pragma unroll
          for (int c = 0; c < 4; ++c) {
            const int cl  = c * 16 + l16;       // 0..63 within pass
            const int kg  = cl >> 3, e = cl & 7;
            #pragma unroll
            for (int i = 0; i < 4; ++i) {
              const int row = wr * 64 + r * 16 + quad * 4 + i;
              float sq = x2v[r][i] + s2v[c] - 2.0f * acc_xs[r][c][i];
              sq = fmaxf(sq, 0.0f);
              smem[ks_base(kg) + row * 8 + e] = f2bf(__expf(-gamma * sq));
              acc_xs[r][c][i] = 0.0f;
            }
          }
      }
      __syncthreads();
      // GEMM2 over this 64-k slice; B-frags straight from L2
      #pragma unroll
      for (int ks = 0; ks < 2; ++ks) {
        const int kg = ks * 4 + quad;
        bf16x8 a2[4], b2[4];
        #pragma unroll
        for (int r = 0; r < 4; ++r)
          a2[r] = *(const bf16x8*)&smem[ks_base(kg) + (wr * 64 + r * 16 + l16) * 8];
        const size_t slab = (size_t)(mtg * 16 + p * 8 + kg);
        #pragma unroll
        for (int c = 0; c < 4; ++c)
          b2[c] = *(const bf16x8*)(hw_ws + (slab * 128 + wc * 64 + c * 16 + l16) * 8);
        #pragma unroll
        for (int r = 0; r < 4; ++r)
          #pragma unroll
          for (int c = 0; c < 4; ++c)
            acc_out[r][c] = __builtin_amdgcn_mfma_f32_16x16x32_bf16(a2[r], b2[c], acc_out[r][c], 0, 0, 0);
      }
      __syncthreads();
    }
  }

  // ---- final: atomic-accumulate scale*acc (+ bias/shift once, by half==0 blocks) ----
  float addv[4];
  #pragma unroll
  for (int c = 0; c < 4; ++c) {
    const int col = wc * 64 + c * 16 + l16;
    addv[c] = (half == 0) ? (vscale * head_b[col] + vshift) : 0.0f;
  }
  #pragma unroll
  for (int r = 0; r < 4; ++r)
    #pragma unroll
    for (int c = 0; c < 4; ++c) {
      const int col = wc * 64 + c * 16 + l16;
      #pragma unroll
      for (int i = 0; i < 4; ++i) {
        const int row = b0 + wr * 64 + r * 16 + quad * 4 + i;
        atomicAdd(&out[(size_t)row * NOUT + col], vscale * acc_out[r][c][i] + addv[c]);
      }
    }
}

// ---------- launch ----------
extern "C" void kernel_launch(void* const* d_in, const int* in_sizes, int n_in,
                              void* d_out, int out_size, void* d_ws, size_t ws_size,
                              hipStream_t stream) {
  const float* x       = (const float*)d_in[0];
  const float* support = (const float*)d_in[1];
  const float* gamma   = (const float*)d_in[2];
  const float* head_w  = (const float*)d_in[3];
  const float* head_b  = (const float*)d_in[4];
  const float* scale   = (const float*)d_in[5];
  const float* shift   = (const float*)d_in[6];
  float* out = (float*)d_out;

  char* w = (char*)d_ws;
  u16*   x_ws  = (u16*)(w);                       // 16,777,216 B
  u16*   s_ws  = (u16*)(w + 16777216);            //  4,194,304 B
  u16*   hw_ws = (u16*)(w + 20971520);            //  1,048,576 B
  float* x2    = (float*)(w + 22020096);          //     65,536 B
  float* s2    = (float*)(w + 22085632);          //     16,384 B

  hipMemsetAsync(out, 0, (size_t)out_size * sizeof(float), stream);
  prep_x <<<256, 256, 0, stream>>>(x, x_ws, x2);
  prep_s <<<64, 256, 0, stream>>>(support, s_ws, s2);
  prep_hw<<<32, 256, 0, stream>>>(head_w, hw_ws);
  rbf_fused<<<1024, 256, 0, stream>>>(x_ws, s_ws, hw_ws, x2, s2, gamma,
                                      head_b, scale, shift, out);
}

// Round 3
// 268.026 us; speedup vs baseline: 3.2523x; 3.2523x over previous
//
#include <hip/hip_runtime.h>

typedef unsigned int u32;
typedef unsigned short u16;
typedef __attribute__((ext_vector_type(8))) __bf16 bf16x8;
typedef __attribute__((ext_vector_type(4))) float f32x4;

#define NB 16384
#define NM 4096
#define ND 512
#define NOUT 128

// ---------- helpers ----------
__device__ __forceinline__ u16 f2bf(float f) {
  u32 u = __float_as_uint(f);
  u += 0x7FFFu + ((u >> 16) & 1u);   // RNE
  return (u16)(u >> 16);
}

__device__ __forceinline__ void stage16(const u16* g, u16* l) {
  __builtin_amdgcn_global_load_lds((__attribute__((address_space(1))) void*)g,
                                   (__attribute__((address_space(3))) void*)l,
                                   16, 0, 0);
}

__device__ __forceinline__ uint4 pack8(float4 v0, float4 v1) {
  uint4 pk;
  pk.x = (u32)f2bf(v0.x) | ((u32)f2bf(v0.y) << 16);
  pk.y = (u32)f2bf(v0.z) | ((u32)f2bf(v0.w) << 16);
  pk.z = (u32)f2bf(v1.x) | ((u32)f2bf(v1.y) << 16);
  pk.w = (u32)f2bf(v1.z) | ((u32)f2bf(v1.w) << 16);
  return pk;
}

// ---------- prep_x: 512 blocks x 32 rows. x_ws [rbig(128)][kg(64)][row(128)][8] ----------
__global__ __launch_bounds__(256) void prep_x(const float* __restrict__ x,
                                              u16* __restrict__ x_ws,
                                              float* __restrict__ x2) {
  __shared__ uint4 t[64 * 32];   // 32 KB, XOR-swizzled: t[kg*32 + ((row+kg)&31)]
  const int tid = threadIdx.x, blk = blockIdx.x;
  const int lane = tid & 63, w = tid >> 6;
  const int rbig = blk >> 2, roff = (blk & 3) * 32;

  #pragma unroll
  for (int p = 0; p < 8; ++p) {
    const int row = p * 4 + w;                      // local row 0..31
    const float* src = x + (size_t)(blk * 32 + row) * ND + lane * 8;
    float4 v0 = *(const float4*)src;
    float4 v1 = *(const float4*)(src + 4);
    float ss = v0.x*v0.x + v0.y*v0.y + v0.z*v0.z + v0.w*v0.w
             + v1.x*v1.x + v1.y*v1.y + v1.z*v1.z + v1.w*v1.w;
    #pragma unroll
    for (int off = 32; off > 0; off >>= 1) ss += __shfl_down(ss, off);
    if (lane == 0) x2[blk * 32 + row] = ss;
    t[lane * 32 + ((row + lane) & 31)] = pack8(v0, v1);   // kg = lane
  }
  __syncthreads();
  #pragma unroll
  for (int p = 0; p < 8; ++p) {
    const int kg = p * 8 + (tid >> 5);
    const int row = tid & 31;
    uint4 pk = t[kg * 32 + ((row + kg) & 31)];
    *(uint4*)&x_ws[(((size_t)(rbig * 64 + kg)) * 128 + roff + row) * 8] = pk;
  }
}

// ---------- prep_s: 128 blocks x 32 rows. s_ws [mb(32)][kg(64)][m(128)][8] ----------
__global__ __launch_bounds__(256) void prep_s(const float* __restrict__ s,
                                              u16* __restrict__ s_ws,
                                              float* __restrict__ s2) {
  __shared__ uint4 t[64 * 32];
  const int tid = threadIdx.x, blk = blockIdx.x;
  const int lane = tid & 63, w = tid >> 6;
  const int mb = blk >> 2, moff = (blk & 3) * 32;

  #pragma unroll
  for (int p = 0; p < 8; ++p) {
    const int row = p * 4 + w;
    const float* src = s + (size_t)(blk * 32 + row) * ND + lane * 8;
    float4 v0 = *(const float4*)src;
    float4 v1 = *(const float4*)(src + 4);
    float ss = v0.x*v0.x + v0.y*v0.y + v0.z*v0.z + v0.w*v0.w
             + v1.x*v1.x + v1.y*v1.y + v1.z*v1.z + v1.w*v1.w;
    #pragma unroll
    for (int off = 32; off > 0; off >>= 1) ss += __shfl_down(ss, off);
    if (lane == 0) s2[blk * 32 + row] = ss;
    t[lane * 32 + ((row + lane) & 31)] = pack8(v0, v1);
  }
  __syncthreads();
  #pragma unroll
  for (int p = 0; p < 8; ++p) {
    const int kg = p * 8 + (tid >> 5);
    const int row = tid & 31;
    uint4 pk = t[kg * 32 + ((row + kg) & 31)];
    *(uint4*)&s_ws[(((size_t)(mb * 64 + kg)) * 128 + moff + row) * 8] = pk;
  }
}

// ---------- prep_hw: 32 blocks, m-chunk of 128. hw_ws [slab=(mb*16+kg)][o(128)][8] ----------
__global__ __launch_bounds__(256) void prep_hw(const float* __restrict__ hw,
                                               u16* __restrict__ hw_ws) {
  __shared__ uint4 t[128 * 16];   // 32 KB, swizzled t[o*16 + ((kg+o)&15)]
  const int tid = threadIdx.x, blk = blockIdx.x;
  #pragma unroll
  for (int p = 0; p < 8; ++p) {
    const int o = p * 16 + (tid >> 4);
    const int kg = tid & 15;
    const float* src = hw + (size_t)o * NM + blk * 128 + kg * 8;
    float4 v0 = *(const float4*)src;
    float4 v1 = *(const float4*)(src + 4);
    t[o * 16 + ((kg + o) & 15)] = pack8(v0, v1);
  }
  __syncthreads();
  #pragma unroll
  for (int it = 0; it < 8; ++it) {
    const int kg = it * 2 + (tid >> 7);
    const int o = tid & 127;
    uint4 pk = t[o * 16 + ((kg + o) & 15)];
    *(uint4*)&hw_ws[(((size_t)(blk * 16 + kg)) * 128 + o) * 8] = pk;
  }
}

// ---------- main fused kernel ----------
// grid 1024: rb = bid>>3 (128 row-blocks of 128 rows), half = bid&7 (M split 8x, 4 mtiles each)
// block 256 = 4 waves; wave tile 64x64 (4x4 16x16x32 mfma frags)
// LDS 32 KB: Xbuf[2] (8 KB ea) + Sbuf[2] (8 KB ea); Ks (16 KB) aliases buf1.
// NOTE: launch_bounds (256,2) — the (256,4) variant capped regs at 128 and spilled
// accumulators to scratch (2 GB of HBM writes, 6x regression). At ~116 actual VGPRs
// the HW reaches 4 blocks/CU on its own.
__global__ __launch_bounds__(256, 2)
void rbf_fused(const u16* __restrict__ x_ws, const u16* __restrict__ s_ws,
               const u16* __restrict__ hw_ws, const float* __restrict__ x2,
               const float* __restrict__ s2, const float* __restrict__ gamma_p,
               const float* __restrict__ head_b, const float* __restrict__ scale_p,
               const float* __restrict__ shift_p, float* __restrict__ out)
{
  __shared__ __align__(16) u16 smem[16384];   // 32 KB

  const int tid  = threadIdx.x;
  const int w    = tid >> 6;
  const int lane = tid & 63;
  const int quad = lane >> 4;
  const int l16  = lane & 15;
  const int wr   = w & 1;
  const int wc   = w >> 1;
  const int rb   = blockIdx.x >> 3;
  const int half = blockIdx.x & 7;
  const int b0   = rb * 128;

  const float gamma  = gamma_p[0];
  const float vscale = scale_p[0];
  const float vshift = shift_p[0];

  // per-thread fixed staging assignment: slabs i = {w, 4+w} (X), {8+w, 12+w} (S)
  // -> kgl0 = w>>1, kgl1 = 2+(w>>1), sub = w&1 for both X and S
  const int sub  = w & 1;
  const int kgl0 = w >> 1;
  const int kgl1 = 2 + (w >> 1);
  const u16* xbase = x_ws + ((size_t)rb * 64 * 128 + sub * 64 + lane) * 8;
  const u16* sbase = s_ws + ((size_t)half * 4) * 65536 + ((size_t)(sub * 64 + lane)) * 8;
  const int dst0 = (kgl0 * 128 + sub * 64 + lane) * 8;   // u16 offset within a buf
  const int dst1 = (kgl1 * 128 + sub * 64 + lane) * 8;

  const f32x4 zf = {0.f, 0.f, 0.f, 0.f};
  f32x4 acc_xs[4][4];
  f32x4 acc_out[4][4];
  #pragma unroll
  for (int r = 0; r < 4; ++r)
    #pragma unroll
    for (int c = 0; c < 4; ++c) { acc_xs[r][c] = zf; acc_out[r][c] = zf; }

  // Ks region: kg<4 lives in Xbuf[1], kg>=4 in Sbuf[1] (each kg = 1024 u16)
  auto ks_base = [&](int kg) { return (kg < 4) ? (4096 + kg * 1024) : (12288 + (kg - 4) * 1024); };

  auto stage_chunk = [&](int g) {
    const int kc  = g & 15;
    const int mt  = g >> 4;
    const int buf = g & 1;
    const u16* xs = xbase + (size_t)(kc * 4) * 1024;
    const u16* ss = sbase + (size_t)mt * 65536 + (size_t)(kc * 4) * 1024;
    stage16(xs + kgl0 * 1024, &smem[buf * 4096 + dst0]);
    stage16(xs + kgl1 * 1024, &smem[buf * 4096 + dst1]);
    stage16(ss + kgl0 * 1024, &smem[8192 + buf * 4096 + dst0]);
    stage16(ss + kgl1 * 1024, &smem[8192 + buf * 4096 + dst1]);
  };

  auto compute_chunk = [&](int buf) {
    bf16x8 av[4], bv[4];
    #pragma unroll
    for (int r = 0; r < 4; ++r)
      av[r] = *(const bf16x8*)&smem[buf * 4096 + (quad * 128 + wr * 64 + r * 16 + l16) * 8];
    #pragma unroll
    for (int c = 0; c < 4; ++c)
      bv[c] = *(const bf16x8*)&smem[8192 + buf * 4096 + (quad * 128 + wc * 64 + c * 16 + l16) * 8];
    #pragma unroll
    for (int r = 0; r < 4; ++r)
      #pragma unroll
      for (int c = 0; c < 4; ++c)
        acc_xs[r][c] = __builtin_amdgcn_mfma_f32_16x16x32_bf16(av[r], bv[c], acc_xs[r][c], 0, 0, 0);
  };

  stage_chunk(0);
  __syncthreads();

  #pragma unroll 1
  for (int mt = 0; mt < 4; ++mt) {
    const int mtg = half * 4 + mt;
    #pragma unroll 2
    for (int kc = 0; kc < 16; ++kc) {
      const int g = (mt << 4) | kc;
      if (g + 1 < 64) stage_chunk(g + 1);
      compute_chunk(g & 1);
      __syncthreads();
    }

    // two passes: p-th 64 k-columns of this mtile
    #pragma unroll 1
    for (int p = 0; p < 2; ++p) {
      if (wc == p) {
        float s2v[4];
        #pragma unroll
        for (int c = 0; c < 4; ++c)
          s2v[c] = s2[mtg * 128 + wc * 64 + c * 16 + l16];
        #pragma unroll
        for (int r = 0; r < 4; ++r) {
          const f32x4 xv = *(const f32x4*)&x2[b0 + wr * 64 + r * 16 + quad * 4];
          #pragma unroll
          for (int c = 0; c < 4; ++c) {
            const int cl  = c * 16 + l16;       // 0..63 within pass
            const int kg  = cl >> 3, e = cl & 7;
            #pragma unroll
            for (int i = 0; i < 4; ++i) {
              const int row = wr * 64 + r * 16 + quad * 4 + i;
              float sq = xv[i] + s2v[c] - 2.0f * acc_xs[r][c][i];
              sq = fmaxf(sq, 0.0f);
              smem[ks_base(kg) + row * 8 + e] = f2bf(__expf(-gamma * sq));
              acc_xs[r][c][i] = 0.0f;
            }
          }
        }
      }
      __syncthreads();
      // GEMM2 over this 64-k slice; B-frags straight from L2
      #pragma unroll
      for (int ks = 0; ks < 2; ++ks) {
        const int kg = ks * 4 + quad;
        bf16x8 a2[4], b2[4];
        #pragma unroll
        for (int r = 0; r < 4; ++r)
          a2[r] = *(const bf16x8*)&smem[ks_base(kg) + (wr * 64 + r * 16 + l16) * 8];
        const size_t slab = (size_t)(mtg * 16 + p * 8 + kg);
        #pragma unroll
        for (int c = 0; c < 4; ++c)
          b2[c] = *(const bf16x8*)(hw_ws + (slab * 128 + wc * 64 + c * 16 + l16) * 8);
        #pragma unroll
        for (int r = 0; r < 4; ++r)
          #pragma unroll
          for (int c = 0; c < 4; ++c)
            acc_out[r][c] = __builtin_amdgcn_mfma_f32_16x16x32_bf16(a2[r], b2[c], acc_out[r][c], 0, 0, 0);
      }
      __syncthreads();
    }
  }

  // ---- final: atomic-accumulate scale*acc (+ bias/shift once, by half==0 blocks) ----
  float addv[4];
  #pragma unroll
  for (int c = 0; c < 4; ++c) {
    const int col = wc * 64 + c * 16 + l16;
    addv[c] = (half == 0) ? (vscale * head_b[col] + vshift) : 0.0f;
  }
  #pragma unroll
  for (int r = 0; r < 4; ++r)
    #pragma unroll
    for (int c = 0; c < 4; ++c) {
      const int col = wc * 64 + c * 16 + l16;
      #pragma unroll
      for (int i = 0; i < 4; ++i) {
        const int row = b0 + wr * 64 + r * 16 + quad * 4 + i;
        atomicAdd(&out[(size_t)row * NOUT + col], vscale * acc_out[r][c][i] + addv[c]);
      }
    }
}

// ---------- launch ----------
extern "C" void kernel_launch(void* const* d_in, const int* in_sizes, int n_in,
                              void* d_out, int out_size, void* d_ws, size_t ws_size,
                              hipStream_t stream) {
  const float* x       = (const float*)d_in[0];
  const float* support = (const float*)d_in[1];
  const float* gamma   = (const float*)d_in[2];
  const float* head_w  = (const float*)d_in[3];
  const float* head_b  = (const float*)d_in[4];
  const float* scale   = (const float*)d_in[5];
  const float* shift   = (const float*)d_in[6];
  float* out = (float*)d_out;

  char* w = (char*)d_ws;
  u16*   x_ws  = (u16*)(w);                       // 16,777,216 B
  u16*   s_ws  = (u16*)(w + 16777216);            //  4,194,304 B
  u16*   hw_ws = (u16*)(w + 20971520);            //  1,048,576 B
  float* x2    = (float*)(w + 22020096);          //     65,536 B
  float* s2    = (float*)(w + 22085632);          //     16,384 B

  hipMemsetAsync(out, 0, (size_t)out_size * sizeof(float), stream);
  prep_x <<<512, 256, 0, stream>>>(x, x_ws, x2);
  prep_s <<<128, 256, 0, stream>>>(support, s_ws, s2);
  prep_hw<<<32, 256, 0, stream>>>(head_w, hw_ws);
  rbf_fused<<<1024, 256, 0, stream>>>(x_ws, s_ws, hw_ws, x2, s2, gamma,
                                      head_b, scale, shift, out);
}